// Round 1
// 671.874 us; speedup vs baseline: 1.0226x; 1.0226x over previous
//
#include <hip/hip_runtime.h>
#include <cstdint>
#include <cmath>
#include <cstring>
#include <map>
#include <tuple>
#include <vector>

#define SIG_LEN 32768
#define N_KERNELS 2000
#define TILES 32
#define TILE_W 1024
#define CCH 4          // channels (conv kernels of same (k,d,p) group) per block
#define MAXJOBS 2048   // worst case: 2 * (2000/4 + #groups) ~ 1144

// Chunk-job: one (sample, group, 4-channel chunk). 16 bytes.
struct JobC { int out_base; unsigned short widx[4]; unsigned meta; };

// ---------------- host-side replication of np.random.RandomState(0) ----------
namespace nprng {
struct MT {
  uint32_t key[624]; int pos; bool has_gauss;
  void seed(uint32_t s) {
    for (int i = 0; i < 624; i++) { key[i] = s; s = 1812433253u * (s ^ (s >> 30)) + (uint32_t)i + 1u; }
    pos = 624; has_gauss = false;
  }
  void gen() {
    const uint32_t UM = 0x80000000u, LM = 0x7fffffffu, MA = 0x9908b0dfu;
    for (int i = 0; i < 624; i++) {
      uint32_t y = (key[i] & UM) | (key[(i + 1) % 624] & LM);
      key[i] = key[(i + 397) % 624] ^ (y >> 1) ^ ((y & 1u) ? MA : 0u);
    }
    pos = 0;
  }
  uint32_t next32() {
    if (pos == 624) gen();
    uint32_t y = key[pos++];
    y ^= y >> 11; y ^= (y << 7) & 0x9d2c5680u; y ^= (y << 15) & 0xefc60000u; y ^= y >> 18;
    return y;
  }
  double nextD() {
    uint32_t a = next32() >> 5, b = next32() >> 6;
    return ((double)a * 67108864.0 + (double)b) / 9007199254740992.0;
  }
  // numpy legacy randint (rk_interval-compatible): masked rejection over
  // SINGLE 32-bit draws when rng fits in 32 bits (stream-compat w/ numpy<=1.16).
  uint32_t bounded(uint32_t rng) {
    uint32_t mask = rng;
    mask |= mask >> 1; mask |= mask >> 2; mask |= mask >> 4;
    mask |= mask >> 8; mask |= mask >> 16;
    uint32_t v;
    do { v = next32() & mask; } while (v > rng);
    return v;
  }
  // numpy legacy_gauss (polar), values discarded — only stream position matters
  void consume_gauss(int n) {
    for (int i = 0; i < n; i++) {
      if (has_gauss) { has_gauss = false; continue; }
      double x1, x2, r2;
      do {
        x1 = 2.0 * nextD() - 1.0;
        x2 = 2.0 * nextD() - 1.0;
        r2 = x1 * x1 + x2 * x2;
      } while (r2 >= 1.0 || r2 == 0.0);
      has_gauss = true;
    }
  }
};
} // namespace nprng

static JobC g_jobs[MAXJOBS];
static int g_njobs = 0;

static void build_jobs() {
  nprng::MT mt; mt.seed(0);
  static const int KS[3] = {7, 9, 11};
  int K[N_KERNELS], D[N_KERNELS], P[N_KERNELS], E[N_KERNELS];
  for (int i = 0; i < N_KERNELS; i++) {
    int k = KS[(int)mt.bounded(2)];                       // rng.choice((7,9,11))
    int M = (int)std::log2((double)(SIG_LEN - 1) / (double)(k - 1)); // 12/11/11
    int e = (int)mt.bounded((uint32_t)(M - 1));           // rng.randint(0, M)
    int d = 1 << e;
    double r = mt.nextD();                                // rng.rand()
    int p = (r <= 0.5) ? 0 : ((k - 1) * d / 2);
    mt.nextD();                                           // rng.uniform(-1,1) bias
    mt.consume_gauss(k);                                  // rng.normal(size=k)
    K[i] = k; D[i] = d; P[i] = p; E[i] = e;
  }
  std::map<std::tuple<int, int, int>, std::vector<int>> groups;
  for (int i = 0; i < N_KERNELS; i++)
    groups[std::make_tuple(K[i], D[i], P[i])].push_back(i);
  long long off = 0; int jn = 0;
  for (auto& kv : groups) {
    int k = std::get<0>(kv.first), d = std::get<1>(kv.first), p = std::get<2>(kv.first);
    int out_len = SIG_LEN + 2 * p - d * (k - 1);
    auto& v = kv.second;
    int ng = (int)v.size();
    int kcode = (k - 7) / 2;
    int e = E[v[0]];
    for (int n = 0; n < 2; n++) {
      for (int c0 = 0; c0 < ng; c0 += CCH) {
        int cact = (ng - c0 < CCH) ? (ng - c0) : CCH;
        JobC& j = g_jobs[jn++];
        j.out_base = (int)(off + (long long)(n * ng + c0) * out_len);
        for (int c = 0; c < CCH; c++)
          j.widx[c] = (unsigned short)v[c0 + (c < cact ? c : cact - 1)]; // pad = repeat last
        j.meta = (unsigned)kcode | ((unsigned)e << 2) | ((unsigned)(p ? 1 : 0) << 6)
               | ((unsigned)n << 7) | ((unsigned)(cact - 1) << 8);
      }
    }
    off += 2LL * ng * out_len;
  }
  g_njobs = jn;
}

// ------------------------------- device side ---------------------------------
// 4-byte-aligned float4: tap addresses (t + q*d - p) are only 4B aligned when
// d in {1,2} or odd p; gfx950 handles underaligned global dwordx4.
typedef float f4 __attribute__((ext_vector_type(4), aligned(4)));

template <int K>
__device__ __forceinline__ void conv4(const float* __restrict__ xs,
                                      const float* __restrict__ W,
                                      const float* __restrict__ B,
                                      const int* widx, int cact,
                                      int d, int p, int out_len, int tbase,
                                      float* __restrict__ op) {
  // Uniform weight/bias loads (widx from readfirstlane'd job) -> s_load.
  float w[CCH][K]; float bias[CCH];
#pragma unroll
  for (int c = 0; c < CCH; c++) {
    const float* wr = W + widx[c] * 11;
#pragma unroll
    for (int q = 0; q < K; q++) w[c][q] = wr[q];
    bias[c] = B[widx[c]];
  }
  int tid = threadIdx.x;
  int t0 = tbase + 4 * tid;                 // 4 contiguous outputs per thread
  bool fast = (tbase + TILE_W <= out_len) && (tbase >= p) &&
              (tbase + (TILE_W - 1) + (K - 1) * d - p < SIG_LEN);
  if (fast) {
    const float* xp = xs + (t0 - p);
    f4 a[CCH];
#pragma unroll
    for (int c = 0; c < CCH; c++) { a[c] = (f4){bias[c], bias[c], bias[c], bias[c]}; }
#pragma unroll
    for (int q = 0; q < K; q++) {
      f4 xv = *(const f4*)xp;               // one dwordx4 serves 4 outputs x 4 channels
      xp += d;
#pragma unroll
      for (int c = 0; c < CCH; c++) a[c] += w[c][q] * xv;  // v_fmac, 1 sgpr operand
    }
#pragma unroll
    for (int c = 0; c < CCH; c++) {
      if (c < cact) {                       // uniform branch (tail chunks only)
        float* o = op + c * out_len + t0;
        __builtin_nontemporal_store(a[c], (f4*)o);
      }
    }
  } else {
    // Edge tiles (~8% of blocks): scalar, fully predicated.
#pragma unroll
    for (int s = 0; s < 4; s++) {
      int t = t0 + s;
      if (t < out_len) {
        float acc[CCH];
#pragma unroll
        for (int c = 0; c < CCH; c++) acc[c] = bias[c];
#pragma unroll
        for (int q = 0; q < K; q++) {
          int idx = t + q * d - p;
          if ((unsigned)idx < (unsigned)SIG_LEN) {
            float xv = xs[idx];
#pragma unroll
            for (int c = 0; c < CCH; c++) acc[c] += w[c][q] * xv;
          }
        }
#pragma unroll
        for (int c = 0; c < CCH; c++)
          if (c < cact) __builtin_nontemporal_store(acc[c], op + c * out_len + t);
      }
    }
  }
}

__global__ __launch_bounds__(256) void rocket_kernel(const float* __restrict__ x,
                                                     const float* __restrict__ W,
                                                     const float* __restrict__ B,
                                                     const JobC* __restrict__ jobs,
                                                     float* __restrict__ out) {
  int jb = blockIdx.x >> 5;            // / TILES
  int tile = blockIdx.x & (TILES - 1); // % TILES
  const int4* jp = (const int4*)jobs;
  int4 jraw = jp[jb];                  // uniform -> s_load_dwordx4
  int out_base = __builtin_amdgcn_readfirstlane(jraw.x);
  int wp0 = __builtin_amdgcn_readfirstlane(jraw.y);
  int wp1 = __builtin_amdgcn_readfirstlane(jraw.z);
  unsigned meta = (unsigned)__builtin_amdgcn_readfirstlane(jraw.w);
  int widx[CCH] = { wp0 & 0xffff, (wp0 >> 16) & 0xffff,
                    wp1 & 0xffff, (wp1 >> 16) & 0xffff };
  int kcode = meta & 3;
  int e     = (meta >> 2) & 15;
  int pflag = (meta >> 6) & 1;
  int n     = (meta >> 7) & 1;
  int cact  = ((meta >> 8) & 3) + 1;
  int k = 7 + 2 * kcode;
  int d = 1 << e;
  int p = pflag ? (((k - 1) * d) >> 1) : 0;
  int out_len = SIG_LEN + 2 * p - (k - 1) * d;
  int tbase = tile * TILE_W;
  if (tbase >= out_len) return;
  const float* xs = x + n * SIG_LEN;
  float* op = out + out_base;
  if (kcode == 0)      conv4<7>(xs, W, B, widx, cact, d, p, out_len, tbase, op);
  else if (kcode == 1) conv4<9>(xs, W, B, widx, cact, d, p, out_len, tbase, op);
  else                 conv4<11>(xs, W, B, widx, cact, d, p, out_len, tbase, op);
}

extern "C" void kernel_launch(void* const* d_in, const int* in_sizes, int n_in,
                              void* d_out, int out_size, void* d_ws, size_t ws_size,
                              hipStream_t stream) {
  // Deterministic host-side rebuild every call (no static guards; same work
  // each call). During graph replay the captured H2D memcpy node re-reads
  // g_jobs (static storage, rebuilt identically) — this also re-fills d_ws
  // after the harness re-poisons it.
  build_jobs();
  const float* x = (const float*)d_in[0];
  const float* W = (const float*)d_in[1];
  const float* B = (const float*)d_in[2];
  JobC* jdev = (JobC*)d_ws;
  hipMemcpyAsync(jdev, g_jobs, sizeof(g_jobs), hipMemcpyHostToDevice, stream);
  rocket_kernel<<<dim3(g_njobs * TILES), dim3(256), 0, stream>>>(x, W, B, jdev, (float*)d_out);
}

// Round 2
// 620.975 us; speedup vs baseline: 1.1064x; 1.0820x over previous
//
#include <hip/hip_runtime.h>
#include <cstdint>
#include <cmath>
#include <cstring>
#include <map>
#include <tuple>
#include <vector>

#define SIG_LEN 32768
#define N_KERNELS 2000
#define TILES 32
#define TILE_W 1024
#define CCH 8          // channels (conv kernels of same (k,d,p) group) per block
#define MAXJOBS 1024   // 2 * sum(ceil(ng/8)) over ~66 groups ~ 560

// Chunk-job: one (sample, group, 8-channel chunk). 24 bytes.
struct JobC { int out_base; unsigned meta; unsigned short widx[CCH]; };

// ---------------- host-side replication of np.random.RandomState(0) ----------
namespace nprng {
struct MT {
  uint32_t key[624]; int pos; bool has_gauss;
  void seed(uint32_t s) {
    for (int i = 0; i < 624; i++) { key[i] = s; s = 1812433253u * (s ^ (s >> 30)) + (uint32_t)i + 1u; }
    pos = 624; has_gauss = false;
  }
  void gen() {
    const uint32_t UM = 0x80000000u, LM = 0x7fffffffu, MA = 0x9908b0dfu;
    for (int i = 0; i < 624; i++) {
      uint32_t y = (key[i] & UM) | (key[(i + 1) % 624] & LM);
      key[i] = key[(i + 397) % 624] ^ (y >> 1) ^ ((y & 1u) ? MA : 0u);
    }
    pos = 0;
  }
  uint32_t next32() {
    if (pos == 624) gen();
    uint32_t y = key[pos++];
    y ^= y >> 11; y ^= (y << 7) & 0x9d2c5680u; y ^= (y << 15) & 0xefc60000u; y ^= y >> 18;
    return y;
  }
  double nextD() {
    uint32_t a = next32() >> 5, b = next32() >> 6;
    return ((double)a * 67108864.0 + (double)b) / 9007199254740992.0;
  }
  // numpy legacy randint (rk_interval-compatible): masked rejection over
  // SINGLE 32-bit draws when rng fits in 32 bits (stream-compat w/ numpy<=1.16).
  uint32_t bounded(uint32_t rng) {
    uint32_t mask = rng;
    mask |= mask >> 1; mask |= mask >> 2; mask |= mask >> 4;
    mask |= mask >> 8; mask |= mask >> 16;
    uint32_t v;
    do { v = next32() & mask; } while (v > rng);
    return v;
  }
  // numpy legacy_gauss (polar), values discarded — only stream position matters
  void consume_gauss(int n) {
    for (int i = 0; i < n; i++) {
      if (has_gauss) { has_gauss = false; continue; }
      double x1, x2, r2;
      do {
        x1 = 2.0 * nextD() - 1.0;
        x2 = 2.0 * nextD() - 1.0;
        r2 = x1 * x1 + x2 * x2;
      } while (r2 >= 1.0 || r2 == 0.0);
      has_gauss = true;
    }
  }
};
} // namespace nprng

static JobC g_jobs[MAXJOBS];
static int g_njobs = 0;

static void build_jobs() {
  nprng::MT mt; mt.seed(0);
  static const int KS[3] = {7, 9, 11};
  int K[N_KERNELS], D[N_KERNELS], P[N_KERNELS], E[N_KERNELS];
  for (int i = 0; i < N_KERNELS; i++) {
    int k = KS[(int)mt.bounded(2)];                       // rng.choice((7,9,11))
    int M = (int)std::log2((double)(SIG_LEN - 1) / (double)(k - 1)); // 12/11/11
    int e = (int)mt.bounded((uint32_t)(M - 1));           // rng.randint(0, M)
    int d = 1 << e;
    double r = mt.nextD();                                // rng.rand()
    int p = (r <= 0.5) ? 0 : ((k - 1) * d / 2);
    mt.nextD();                                           // rng.uniform(-1,1) bias
    mt.consume_gauss(k);                                  // rng.normal(size=k)
    K[i] = k; D[i] = d; P[i] = p; E[i] = e;
  }
  std::map<std::tuple<int, int, int>, std::vector<int>> groups;
  for (int i = 0; i < N_KERNELS; i++)
    groups[std::make_tuple(K[i], D[i], P[i])].push_back(i);
  long long off = 0; int jn = 0;
  for (auto& kv : groups) {
    int k = std::get<0>(kv.first), d = std::get<1>(kv.first), p = std::get<2>(kv.first);
    int out_len = SIG_LEN + 2 * p - d * (k - 1);
    auto& v = kv.second;
    int ng = (int)v.size();
    int kcode = (k - 7) / 2;
    int e = E[v[0]];
    for (int n = 0; n < 2; n++) {
      for (int c0 = 0; c0 < ng; c0 += CCH) {
        int cact = (ng - c0 < CCH) ? (ng - c0) : CCH;
        JobC& j = g_jobs[jn++];
        j.out_base = (int)(off + (long long)(n * ng + c0) * out_len);
        for (int c = 0; c < CCH; c++)
          j.widx[c] = (unsigned short)v[c0 + (c < cact ? c : cact - 1)]; // pad = repeat last
        j.meta = (unsigned)kcode | ((unsigned)e << 2) | ((unsigned)(p ? 1 : 0) << 6)
               | ((unsigned)n << 7) | ((unsigned)(cact - 1) << 8);
      }
    }
    off += 2LL * ng * out_len;
  }
  g_njobs = jn;
}

// ------------------------------- device side ---------------------------------
// 4-byte-aligned float4: tap addresses (t + q*d - p) are only 4B aligned when
// d in {1,2} or odd p; gfx950 handles underaligned global dwordx4.
typedef float f4 __attribute__((ext_vector_type(4), aligned(4)));

template <int K>
__device__ __forceinline__ void conv8(const float* __restrict__ xs,
                                      const float* __restrict__ W,
                                      const float* __restrict__ B,
                                      const int* widx, int cact,
                                      int d, int p, int out_len, int tbase,
                                      float* __restrict__ op) {
  // Uniform weight/bias loads (widx from readfirstlane'd job) -> s_load.
  float w[CCH][K]; float bias[CCH];
#pragma unroll
  for (int c = 0; c < CCH; c++) {
    const float* wr = W + widx[c] * 11;
#pragma unroll
    for (int q = 0; q < K; q++) w[c][q] = wr[q];
    bias[c] = B[widx[c]];
  }
  int tid = threadIdx.x;
  int t0 = tbase + 4 * tid;                 // 4 contiguous outputs per thread
  bool fast = (tbase + TILE_W <= out_len) && (tbase >= p) &&
              (tbase + (TILE_W - 1) + (K - 1) * d - p < SIG_LEN);
  if (fast) {
    const float* xp = xs + (t0 - p);
    f4 a[CCH];
#pragma unroll
    for (int c = 0; c < CCH; c++) { a[c] = (f4){bias[c], bias[c], bias[c], bias[c]}; }
#pragma unroll
    for (int q = 0; q < K; q++) {
      f4 xv = *(const f4*)xp;               // one dwordx4 serves 4 outputs x 8 channels
      xp += d;
#pragma unroll
      for (int c = 0; c < CCH; c++) a[c] += w[c][q] * xv;  // v_fmac, 1 sgpr operand
    }
#pragma unroll
    for (int c = 0; c < CCH; c++) {
      if (c < cact) {                       // uniform branch (tail chunks only)
        float* o = op + c * out_len + t0;
        __builtin_nontemporal_store(a[c], (f4*)o);
      }
    }
  } else {
    // Edge tiles (~8% of blocks): scalar, fully predicated.
#pragma unroll
    for (int s = 0; s < 4; s++) {
      int t = t0 + s;
      if (t < out_len) {
        float acc[CCH];
#pragma unroll
        for (int c = 0; c < CCH; c++) acc[c] = bias[c];
#pragma unroll
        for (int q = 0; q < K; q++) {
          int idx = t + q * d - p;
          if ((unsigned)idx < (unsigned)SIG_LEN) {
            float xv = xs[idx];
#pragma unroll
            for (int c = 0; c < CCH; c++) acc[c] += w[c][q] * xv;
          }
        }
#pragma unroll
        for (int c = 0; c < CCH; c++)
          if (c < cact) __builtin_nontemporal_store(acc[c], op + c * out_len + t);
      }
    }
  }
}

__global__ __launch_bounds__(256) void rocket_kernel(const float* __restrict__ x,
                                                     const float* __restrict__ W,
                                                     const float* __restrict__ B,
                                                     const JobC* __restrict__ jobs,
                                                     float* __restrict__ out) {
  int jb = blockIdx.x >> 5;            // / TILES
  int tile = blockIdx.x & (TILES - 1); // % TILES
  const int* jp = (const int*)(jobs + jb);   // uniform address -> s_load
  int out_base  = __builtin_amdgcn_readfirstlane(jp[0]);
  unsigned meta = (unsigned)__builtin_amdgcn_readfirstlane(jp[1]);
  int wp0 = __builtin_amdgcn_readfirstlane(jp[2]);
  int wp1 = __builtin_amdgcn_readfirstlane(jp[3]);
  int wp2 = __builtin_amdgcn_readfirstlane(jp[4]);
  int wp3 = __builtin_amdgcn_readfirstlane(jp[5]);
  int widx[CCH] = { wp0 & 0xffff, (wp0 >> 16) & 0xffff,
                    wp1 & 0xffff, (wp1 >> 16) & 0xffff,
                    wp2 & 0xffff, (wp2 >> 16) & 0xffff,
                    wp3 & 0xffff, (wp3 >> 16) & 0xffff };
  int kcode = meta & 3;
  int e     = (meta >> 2) & 15;
  int pflag = (meta >> 6) & 1;
  int n     = (meta >> 7) & 1;
  int cact  = ((meta >> 8) & 7) + 1;
  int k = 7 + 2 * kcode;
  int d = 1 << e;
  int p = pflag ? (((k - 1) * d) >> 1) : 0;
  int out_len = SIG_LEN + 2 * p - (k - 1) * d;
  int tbase = tile * TILE_W;
  if (tbase >= out_len) return;
  const float* xs = x + n * SIG_LEN;
  float* op = out + out_base;
  if (kcode == 0)      conv8<7>(xs, W, B, widx, cact, d, p, out_len, tbase, op);
  else if (kcode == 1) conv8<9>(xs, W, B, widx, cact, d, p, out_len, tbase, op);
  else                 conv8<11>(xs, W, B, widx, cact, d, p, out_len, tbase, op);
}

extern "C" void kernel_launch(void* const* d_in, const int* in_sizes, int n_in,
                              void* d_out, int out_size, void* d_ws, size_t ws_size,
                              hipStream_t stream) {
  // Deterministic host-side rebuild every call (no static guards; same work
  // each call). During graph replay the captured H2D memcpy node re-reads
  // g_jobs (static storage, rebuilt identically) — this also re-fills d_ws
  // after the harness re-poisons it.
  build_jobs();
  const float* x = (const float*)d_in[0];
  const float* W = (const float*)d_in[1];
  const float* B = (const float*)d_in[2];
  JobC* jdev = (JobC*)d_ws;
  hipMemcpyAsync(jdev, g_jobs, sizeof(g_jobs), hipMemcpyHostToDevice, stream);
  rocket_kernel<<<dim3(g_njobs * TILES), dim3(256), 0, stream>>>(x, W, B, jdev, (float*)d_out);
}

// Round 3
// 604.256 us; speedup vs baseline: 1.1370x; 1.0277x over previous
//
#include <hip/hip_runtime.h>
#include <cstdint>
#include <cmath>
#include <cstring>
#include <map>
#include <tuple>
#include <vector>

#define SIG_LEN 32768
#define N_KERNELS 2000
#define TILES 32
#define TILE_W 1024
#define CCH 8            // channels (conv kernels of same (k,d,p) group) per block
#define MAXG 80          // distinct (k,d,p) groups: <= 68
#define WPACK_WORDS 688  // ceil(2000*11/32)

// Per-group record (12 B). All job decode happens on-device from blockIdx.
struct GroupRec {
  int out_base;          // element offset of this group's output block
  unsigned short ng;     // #channels in group
  unsigned short wstart; // index of first channel in packed widx stream
  unsigned short cum;    // #8-channel chunks before this group
  unsigned char meta;    // kcode(2) | e<<2 (4) | pflag<<6 (1)
  unsigned char pad;
};
// Whole job table passed by value in the kernarg segment (~3.7 KB < 4 KB).
// Captured once at graph capture; replay reuses the snapshot -> no H2D node.
struct Args {
  int n_groups;
  int total_chunks;
  GroupRec g[MAXG];
  unsigned wpack[WPACK_WORDS]; // 2000 channel ids, 11-bit packed, group order
};

// ---------------- host-side replication of np.random.RandomState(0) ----------
namespace nprng {
struct MT {
  uint32_t key[624]; int pos; bool has_gauss;
  void seed(uint32_t s) {
    for (int i = 0; i < 624; i++) { key[i] = s; s = 1812433253u * (s ^ (s >> 30)) + (uint32_t)i + 1u; }
    pos = 624; has_gauss = false;
  }
  void gen() {
    const uint32_t UM = 0x80000000u, LM = 0x7fffffffu, MA = 0x9908b0dfu;
    for (int i = 0; i < 624; i++) {
      uint32_t y = (key[i] & UM) | (key[(i + 1) % 624] & LM);
      key[i] = key[(i + 397) % 624] ^ (y >> 1) ^ ((y & 1u) ? MA : 0u);
    }
    pos = 0;
  }
  uint32_t next32() {
    if (pos == 624) gen();
    uint32_t y = key[pos++];
    y ^= y >> 11; y ^= (y << 7) & 0x9d2c5680u; y ^= (y << 15) & 0xefc60000u; y ^= y >> 18;
    return y;
  }
  double nextD() {
    uint32_t a = next32() >> 5, b = next32() >> 6;
    return ((double)a * 67108864.0 + (double)b) / 9007199254740992.0;
  }
  // numpy legacy randint (rk_interval-compatible): masked rejection over
  // SINGLE 32-bit draws when rng fits in 32 bits (stream-compat w/ numpy<=1.16).
  uint32_t bounded(uint32_t rng) {
    uint32_t mask = rng;
    mask |= mask >> 1; mask |= mask >> 2; mask |= mask >> 4;
    mask |= mask >> 8; mask |= mask >> 16;
    uint32_t v;
    do { v = next32() & mask; } while (v > rng);
    return v;
  }
  // numpy legacy_gauss (polar), values discarded — only stream position matters
  void consume_gauss(int n) {
    for (int i = 0; i < n; i++) {
      if (has_gauss) { has_gauss = false; continue; }
      double x1, x2, r2;
      do {
        x1 = 2.0 * nextD() - 1.0;
        x2 = 2.0 * nextD() - 1.0;
        r2 = x1 * x1 + x2 * x2;
      } while (r2 >= 1.0 || r2 == 0.0);
      has_gauss = true;
    }
  }
};
} // namespace nprng

static Args g_args;
static int g_grid = 0;

static void put11(int i, unsigned v) {
  int bp = i * 11, w = bp >> 5, sh = bp & 31;
  g_args.wpack[w] |= v << sh;
  if (sh > 21) g_args.wpack[w + 1] |= v >> (32 - sh);
}

static void build_jobs() {
  nprng::MT mt; mt.seed(0);
  static const int KS[3] = {7, 9, 11};
  int K[N_KERNELS], D[N_KERNELS], P[N_KERNELS], E[N_KERNELS];
  for (int i = 0; i < N_KERNELS; i++) {
    int k = KS[(int)mt.bounded(2)];                       // rng.choice((7,9,11))
    int M = (int)std::log2((double)(SIG_LEN - 1) / (double)(k - 1)); // 12/11/11
    int e = (int)mt.bounded((uint32_t)(M - 1));           // rng.randint(0, M)
    int d = 1 << e;
    double r = mt.nextD();                                // rng.rand()
    int p = (r <= 0.5) ? 0 : ((k - 1) * d / 2);
    mt.nextD();                                           // rng.uniform(-1,1) bias
    mt.consume_gauss(k);                                  // rng.normal(size=k)
    K[i] = k; D[i] = d; P[i] = p; E[i] = e;
  }
  std::map<std::tuple<int, int, int>, std::vector<int>> groups;
  for (int i = 0; i < N_KERNELS; i++)
    groups[std::make_tuple(K[i], D[i], P[i])].push_back(i);
  std::memset(&g_args, 0, sizeof(g_args));
  long long off = 0; int gi = 0, wpos = 0, cum = 0;
  for (auto& kv : groups) {
    int k = std::get<0>(kv.first), d = std::get<1>(kv.first), p = std::get<2>(kv.first);
    int out_len = SIG_LEN + 2 * p - d * (k - 1);
    auto& v = kv.second;
    int ng = (int)v.size();
    int kcode = (k - 7) / 2;
    int e = E[v[0]];
    GroupRec& G = g_args.g[gi++];
    G.out_base = (int)off;
    G.ng = (unsigned short)ng;
    G.wstart = (unsigned short)wpos;
    G.cum = (unsigned short)cum;
    G.meta = (unsigned char)(kcode | (e << 2) | ((p ? 1 : 0) << 6));
    for (int c : v) put11(wpos++, (unsigned)c);
    cum += (ng + CCH - 1) / CCH;
    off += 2LL * ng * out_len;
  }
  g_args.n_groups = gi;
  g_args.total_chunks = cum;
  g_grid = cum * 2 * TILES;
}

// ------------------------------- device side ---------------------------------
// 4-byte-aligned float4: tap addresses (t + q*d - p) are only 4B aligned when
// d in {1,2} or odd p; gfx950 handles underaligned global dwordx4.
typedef float f4 __attribute__((ext_vector_type(4), aligned(4)));

template <int K>
__device__ __forceinline__ void conv8(const float* __restrict__ xs,
                                      const float* __restrict__ W,
                                      const float* __restrict__ B,
                                      const int* widx, int cact,
                                      int d, int p, int out_len, int tbase,
                                      float* __restrict__ op) {
  // Uniform weight/bias loads (scalar addresses) -> s_load.
  float w[CCH][K]; float bias[CCH];
#pragma unroll
  for (int c = 0; c < CCH; c++) {
    const float* wr = W + widx[c] * 11;
#pragma unroll
    for (int q = 0; q < K; q++) w[c][q] = wr[q];
    bias[c] = B[widx[c]];
  }
  int tid = threadIdx.x;
  int t0 = tbase + 4 * tid;                 // 4 contiguous outputs per thread
  bool fast = (tbase + TILE_W <= out_len) && (tbase >= p) &&
              (tbase + (TILE_W - 1) + (K - 1) * d - p < SIG_LEN);
  if (fast) {
    const float* xp = xs + (t0 - p);
    f4 a[CCH];
#pragma unroll
    for (int c = 0; c < CCH; c++) { a[c] = (f4){bias[c], bias[c], bias[c], bias[c]}; }
#pragma unroll
    for (int q = 0; q < K; q++) {
      f4 xv = *(const f4*)xp;               // one dwordx4 serves 4 outputs x 8 channels
      xp += d;
#pragma unroll
      for (int c = 0; c < CCH; c++) a[c] += w[c][q] * xv;  // v_fmac, 1 sgpr operand
    }
#pragma unroll
    for (int c = 0; c < CCH; c++) {
      if (c < cact) {                       // uniform branch (tail chunks only)
        float* o = op + c * out_len + t0;
        __builtin_nontemporal_store(a[c], (f4*)o);
      }
    }
  } else {
    // Edge tiles (~4% of blocks): scalar, fully predicated.
#pragma unroll
    for (int s = 0; s < 4; s++) {
      int t = t0 + s;
      if (t < out_len) {
        float acc[CCH];
#pragma unroll
        for (int c = 0; c < CCH; c++) acc[c] = bias[c];
#pragma unroll
        for (int q = 0; q < K; q++) {
          int idx = t + q * d - p;
          if ((unsigned)idx < (unsigned)SIG_LEN) {
            float xv = xs[idx];
#pragma unroll
            for (int c = 0; c < CCH; c++) acc[c] += w[c][q] * xv;
          }
        }
#pragma unroll
        for (int c = 0; c < CCH; c++)
          if (c < cact) __builtin_nontemporal_store(acc[c], op + c * out_len + t);
      }
    }
  }
}

__global__ __launch_bounds__(256) void rocket_kernel(const float* __restrict__ x,
                                                     const float* __restrict__ W,
                                                     const float* __restrict__ B,
                                                     float* __restrict__ out,
                                                     Args a) {
  int tile  = blockIdx.x & (TILES - 1);
  int n     = (blockIdx.x >> 5) & 1;
  int chunk = blockIdx.x >> 6;
  // Uniform binary search: largest g with a.g[g].cum <= chunk (7 iters, s_loads)
  int lo = 0, hi = a.n_groups - 1;
  while (lo < hi) {
    int mid = (lo + hi + 1) >> 1;
    if ((int)a.g[mid].cum <= chunk) lo = mid; else hi = mid - 1;
  }
  int out_base_g = a.g[lo].out_base;
  int ng     = a.g[lo].ng;
  int wstart = a.g[lo].wstart;
  int cum    = a.g[lo].cum;
  unsigned meta = a.g[lo].meta;
  int kcode = meta & 3;
  int e     = (meta >> 2) & 15;
  int pflag = (meta >> 6) & 1;
  int c0   = (chunk - cum) * CCH;
  int cact = ng - c0; if (cact > CCH) cact = CCH;
  int k = 7 + 2 * kcode;
  int d = 1 << e;
  int p = pflag ? (((k - 1) * d) >> 1) : 0;
  int out_len = SIG_LEN + 2 * p - (k - 1) * d;
  int tbase = tile * TILE_W;
  if (tbase >= out_len) return;
  // Unpack this chunk's 8 channel ids (11-bit stream, uniform scalar ops).
  int widx[CCH];
#pragma unroll
  for (int cc = 0; cc < CCH; cc++) {
    int sel = (cc < cact) ? cc : (cact - 1);   // pad = repeat last
    int idx = wstart + c0 + sel;
    int bp = idx * 11, wd = bp >> 5, sh = bp & 31;
    unsigned v = a.wpack[wd] >> sh;
    if (sh > 21) v |= a.wpack[wd + 1] << (32 - sh);
    widx[cc] = (int)(v & 0x7FFu);
  }
  const float* xs = x + n * SIG_LEN;
  float* op = out + out_base_g + (n * ng + c0) * out_len;
  if (kcode == 0)      conv8<7>(xs, W, B, widx, cact, d, p, out_len, tbase, op);
  else if (kcode == 1) conv8<9>(xs, W, B, widx, cact, d, p, out_len, tbase, op);
  else                 conv8<11>(xs, W, B, widx, cact, d, p, out_len, tbase, op);
}

extern "C" void kernel_launch(void* const* d_in, const int* in_sizes, int n_in,
                              void* d_out, int out_size, void* d_ws, size_t ws_size,
                              hipStream_t stream) {
  // Deterministic host-side rebuild every call; the job table travels in the
  // kernarg segment (by-value Args), so there is NO H2D memcpy node and d_ws
  // is unused. Graph capture snapshots the kernarg; replay reuses it, which
  // is correct because build_jobs() is deterministic.
  build_jobs();
  const float* x = (const float*)d_in[0];
  const float* W = (const float*)d_in[1];
  const float* B = (const float*)d_in[2];
  rocket_kernel<<<dim3(g_grid), dim3(256), 0, stream>>>(x, W, B, (float*)d_out, g_args);
}